// Round 2
// baseline (721.697 us; speedup 1.0000x reference)
//
#include <hip/hip_runtime.h>

// Problem constants (from reference): N=1048576, D=128, G=4096, HID=50, GDIM=201, TAIL=33
// ALL float tensors are float32 (reference dtype); batch/edge_index are int32.
#define N_ROWS 1048576
#define DIM    128
#define G_SEG  4096
#define HID    50
#define GDIM_  201
#define TAILN  33
#define OUTW   (GDIM_ + TAILN)   // 234
#define U_COLS 64

// Kernel 1: segment start offsets via boundary diff (batch is sorted ascending).
// Writes start[0..G_SEG] inclusive; covers empty segments and head/tail so no
// memset of ws is required (ws is re-poisoned 0xAA before every call).
__global__ void seg_starts_kernel(const int* __restrict__ batch, int* __restrict__ start, int n) {
    int i = blockIdx.x * blockDim.x + threadIdx.x;
    if (i >= n) return;
    int b = batch[i];
    if (i == 0) {
        for (int g = 0; g <= b; ++g) start[g] = 0;
    } else {
        int bp = batch[i - 1];
        for (int g = bp + 1; g <= b; ++g) start[g] = i;
    }
    if (i == n - 1) {
        for (int g = b + 1; g <= G_SEG; ++g) start[g] = n;
    }
}

// Kernel 2: one block per segment. 256 threads = 8 row-groups x 32 feature-groups(4 floats).
__launch_bounds__(256)
__global__ void pna_main_kernel(const float* __restrict__ x,
                                const float* __restrict__ u,
                                const int*   __restrict__ start,
                                const float* __restrict__ W1,
                                const float* __restrict__ b1,
                                const float* __restrict__ lng,
                                const float* __restrict__ lnb,
                                const float* __restrict__ W2,
                                const float* __restrict__ b2,
                                float* __restrict__ out) {
    __shared__ float red[8][128];    // reused for all 4 stats (4 KB)
    __shared__ float aggr[512];      // mean|std|max|min
    __shared__ float part[4][HID];
    __shared__ float hbuf[HID];
    __shared__ float hn[HID];

    const int g  = blockIdx.x;
    const int t  = threadIdx.x;
    const int fg = t & 31;       // feature group -> feats fg*4 .. fg*4+3
    const int rg = t >> 5;       // row group 0..7
    const int r0 = start[g];
    const int r1 = start[g + 1];
    const int cnt = r1 - r0;

    float s[4], s2[4], mx[4], mn[4];
#pragma unroll
    for (int j = 0; j < 4; ++j) { s[j] = 0.f; s2[j] = 0.f; mx[j] = -INFINITY; mn[j] = INFINITY; }

    const int fbase = fg * 4;
    for (int r = r0 + rg; r < r1; r += 8) {
        float4 v = *reinterpret_cast<const float4*>(x + (size_t)r * DIM + fbase);
        float f[4] = {v.x, v.y, v.z, v.w};
#pragma unroll
        for (int j = 0; j < 4; ++j) {
            s[j]  += f[j];
            s2[j]  = fmaf(f[j], f[j], s2[j]);
            mx[j]  = fmaxf(mx[j], f[j]);
            mn[j]  = fminf(mn[j], f[j]);
        }
    }

    const float inv_c = 1.0f / (float)((cnt > 1) ? cnt : 1);

    // --- sum -> mean ---
#pragma unroll
    for (int j = 0; j < 4; ++j) red[rg][fbase + j] = s[j];
    __syncthreads();
    if (t < 128) {
        float a = red[0][t];
#pragma unroll
        for (int k = 1; k < 8; ++k) a += red[k][t];
        aggr[t] = a * inv_c;
    }
    __syncthreads();
    // --- sumsq -> std ---
#pragma unroll
    for (int j = 0; j < 4; ++j) red[rg][fbase + j] = s2[j];
    __syncthreads();
    if (t < 128) {
        float a = red[0][t];
#pragma unroll
        for (int k = 1; k < 8; ++k) a += red[k][t];
        float mean = aggr[t];
        float var  = a * inv_c - mean * mean;
        var = fmaxf(var, 0.0f);                 // jax.nn.relu(var)
        aggr[128 + t] = sqrtf(var + 1e-5f);
    }
    __syncthreads();
    // --- max ---
#pragma unroll
    for (int j = 0; j < 4; ++j) red[rg][fbase + j] = mx[j];
    __syncthreads();
    if (t < 128) {
        float a = red[0][t];
#pragma unroll
        for (int k = 1; k < 8; ++k) a = fmaxf(a, red[k][t]);
        aggr[256 + t] = a;
    }
    __syncthreads();
    // --- min ---
#pragma unroll
    for (int j = 0; j < 4; ++j) red[rg][fbase + j] = mn[j];
    __syncthreads();
    if (t < 128) {
        float a = red[0][t];
#pragma unroll
        for (int k = 1; k < 8; ++k) a = fminf(a, red[k][t]);
        aggr[384 + t] = a;
    }
    __syncthreads();

    // --- GEMM1: h = selu(aggr(1x512) @ W1(512x50) + b1); 4 k-quarters x 50 outputs ---
    if (t < 4 * HID) {
        const int q = t / HID;
        const int j = t - q * HID;
        const int k0 = q * 128;
        float acc = 0.f;
#pragma unroll 8
        for (int k = 0; k < 128; ++k) {
            acc = fmaf(aggr[k0 + k], W1[(size_t)(k0 + k) * HID + j], acc);
        }
        part[q][j] = acc;
    }
    __syncthreads();
    if (t < HID) {
        float acc = part[0][t] + part[1][t] + part[2][t] + part[3][t] + b1[t];
        // selu: scale * (x>0 ? x : alpha*expm1(x))
        float v = acc > 0.f ? acc : 1.6732632423543772f * expm1f(acc);
        hbuf[t] = 1.0507009873554805f * v;
    }
    __syncthreads();
    // --- LayerNorm over HID=50 (each active thread redundantly computes mu/var via LDS) ---
    if (t < HID) {
        float mu = 0.f;
#pragma unroll
        for (int j2 = 0; j2 < HID; ++j2) mu += hbuf[j2];
        mu *= (1.0f / HID);
        float va = 0.f;
#pragma unroll
        for (int j2 = 0; j2 < HID; ++j2) { float d = hbuf[j2] - mu; va = fmaf(d, d, va); }
        va *= (1.0f / HID);
        hn[t] = (hbuf[t] - mu) * rsqrtf(va + 1e-5f) * lng[t] + lnb[t];
    }
    __syncthreads();
    // --- GEMM2: head = hn(1x50) @ W2(50x201) + b2; write head ---
    if (t < GDIM_) {
        float acc = b2[t];
#pragma unroll
        for (int j2 = 0; j2 < HID; ++j2) {
            acc = fmaf(hn[j2], W2[(size_t)j2 * GDIM_ + t], acc);
        }
        out[(size_t)g * OUTW + t] = acc;
    }
    // --- tail: u[:, -33:] bit-exact copy ---
    if (t >= 201 && t < 201 + TAILN) {
        int i2 = t - 201;
        out[(size_t)g * OUTW + GDIM_ + i2] = u[(size_t)g * U_COLS + (U_COLS - TAILN) + i2];
    }
}

extern "C" void kernel_launch(void* const* d_in, const int* in_sizes, int n_in,
                              void* d_out, int out_size, void* d_ws, size_t ws_size,
                              hipStream_t stream) {
    // inputs (setup_inputs order): x, edge_index, edge_attr, u, batch, W1, b1, ln_g, ln_b, W2, b2
    const float* x     = (const float*)d_in[0];
    const float* u     = (const float*)d_in[3];
    const int*   batch = (const int*)d_in[4];
    const float* W1    = (const float*)d_in[5];
    const float* b1    = (const float*)d_in[6];
    const float* lng   = (const float*)d_in[7];
    const float* lnb   = (const float*)d_in[8];
    const float* W2    = (const float*)d_in[9];
    const float* b2    = (const float*)d_in[10];
    float* out = (float*)d_out;
    int* start = (int*)d_ws;   // (G_SEG+1) ints

    seg_starts_kernel<<<N_ROWS / 256, 256, 0, stream>>>(batch, start, N_ROWS);
    pna_main_kernel<<<G_SEG, 256, 0, stream>>>(x, u, start, W1, b1, lng, lnb, W2, b2, out);
}

// Round 3
// 706.058 us; speedup vs baseline: 1.0222x; 1.0222x over previous
//
#include <hip/hip_runtime.h>

// Problem constants: N=1048576, D=128, G=4096, HID=50, GDIM=201, TAIL=33
// All float tensors are float32; batch is int32 (sorted ascending).
#define N_ROWS 1048576
#define DIM    128
#define G_SEG  4096
#define HID    50
#define GDIM_  201
#define TAILN  33
#define OUTW   (GDIM_ + TAILN)   // 234
#define U_COLS 64

typedef float f4 __attribute__((ext_vector_type(4)));

__device__ __forceinline__ int lower_bound_i(const int* __restrict__ a, int n, int key) {
    int lo = 0, hi = n;
    while (lo < hi) {
        int mid = (lo + hi) >> 1;
        if (a[mid] < key) lo = mid + 1; else hi = mid;
    }
    return lo;
}

// One block per segment. 256 threads = 8 row-groups x 32 feature-groups(4 floats).
// Segment bounds found by per-block binary search on the sorted batch array.
__launch_bounds__(256)
__global__ void pna_main_kernel(const float* __restrict__ x,
                                const float* __restrict__ u,
                                const int*   __restrict__ batch,
                                const float* __restrict__ W1,
                                const float* __restrict__ b1,
                                const float* __restrict__ lng,
                                const float* __restrict__ lnb,
                                const float* __restrict__ W2,
                                const float* __restrict__ b2,
                                float* __restrict__ out) {
    __shared__ float red[8][128];    // reused for all 4 stats (4 KB)
    __shared__ float aggr[512];      // mean|std|max|min
    __shared__ float part[4][HID];
    __shared__ float hbuf[HID];
    __shared__ float hn[HID];

    const int g  = blockIdx.x;
    const int t  = threadIdx.x;
    const int fg = t & 31;       // feature group -> feats fg*4 .. fg*4+3
    const int rg = t >> 5;       // row group 0..7

    // All threads redundantly binary-search (same addresses -> broadcast loads).
    const int r0 = lower_bound_i(batch, N_ROWS, g);
    const int r1 = lower_bound_i(batch, N_ROWS, g + 1);
    const int cnt = r1 - r0;

    float s[4], s2[4], mx[4], mn[4];
#pragma unroll
    for (int j = 0; j < 4; ++j) { s[j] = 0.f; s2[j] = 0.f; mx[j] = -INFINITY; mn[j] = INFINITY; }

    const int fbase = fg * 4;
    int r = r0 + rg;
    // Unroll x2: two independent 16B non-temporal loads in flight.
    for (; r + 8 < r1; r += 16) {
        f4 va = __builtin_nontemporal_load(reinterpret_cast<const f4*>(x + (size_t)r * DIM + fbase));
        f4 vb = __builtin_nontemporal_load(reinterpret_cast<const f4*>(x + (size_t)(r + 8) * DIM + fbase));
        float fa[4] = {va.x, va.y, va.z, va.w};
        float fb[4] = {vb.x, vb.y, vb.z, vb.w};
#pragma unroll
        for (int j = 0; j < 4; ++j) {
            s[j] += fa[j];  s2[j] = fmaf(fa[j], fa[j], s2[j]);
            mx[j] = fmaxf(mx[j], fa[j]);  mn[j] = fminf(mn[j], fa[j]);
        }
#pragma unroll
        for (int j = 0; j < 4; ++j) {
            s[j] += fb[j];  s2[j] = fmaf(fb[j], fb[j], s2[j]);
            mx[j] = fmaxf(mx[j], fb[j]);  mn[j] = fminf(mn[j], fb[j]);
        }
    }
    if (r < r1) {
        f4 va = __builtin_nontemporal_load(reinterpret_cast<const f4*>(x + (size_t)r * DIM + fbase));
        float fa[4] = {va.x, va.y, va.z, va.w};
#pragma unroll
        for (int j = 0; j < 4; ++j) {
            s[j] += fa[j];  s2[j] = fmaf(fa[j], fa[j], s2[j]);
            mx[j] = fmaxf(mx[j], fa[j]);  mn[j] = fminf(mn[j], fa[j]);
        }
    }

    const float inv_c = 1.0f / (float)((cnt > 1) ? cnt : 1);

    // --- sum -> mean --- (b128 LDS stores: conflict-free lane pattern)
    *reinterpret_cast<float4*>(&red[rg][fbase]) = make_float4(s[0], s[1], s[2], s[3]);
    __syncthreads();
    if (t < 128) {
        float a = red[0][t];
#pragma unroll
        for (int k = 1; k < 8; ++k) a += red[k][t];
        aggr[t] = a * inv_c;
    }
    __syncthreads();
    // --- sumsq -> std ---
    *reinterpret_cast<float4*>(&red[rg][fbase]) = make_float4(s2[0], s2[1], s2[2], s2[3]);
    __syncthreads();
    if (t < 128) {
        float a = red[0][t];
#pragma unroll
        for (int k = 1; k < 8; ++k) a += red[k][t];
        float mean = aggr[t];
        float var  = a * inv_c - mean * mean;
        var = fmaxf(var, 0.0f);                 // jax.nn.relu(var)
        aggr[128 + t] = sqrtf(var + 1e-5f);
    }
    __syncthreads();
    // --- max ---
    *reinterpret_cast<float4*>(&red[rg][fbase]) = make_float4(mx[0], mx[1], mx[2], mx[3]);
    __syncthreads();
    if (t < 128) {
        float a = red[0][t];
#pragma unroll
        for (int k = 1; k < 8; ++k) a = fmaxf(a, red[k][t]);
        aggr[256 + t] = a;
    }
    __syncthreads();
    // --- min ---
    *reinterpret_cast<float4*>(&red[rg][fbase]) = make_float4(mn[0], mn[1], mn[2], mn[3]);
    __syncthreads();
    if (t < 128) {
        float a = red[0][t];
#pragma unroll
        for (int k = 1; k < 8; ++k) a = fminf(a, red[k][t]);
        aggr[384 + t] = a;
    }
    __syncthreads();

    // --- GEMM1: h = selu(aggr(1x512) @ W1(512x50) + b1); 4 k-quarters x 50 outputs ---
    if (t < 4 * HID) {
        const int q = t / HID;
        const int j = t - q * HID;
        const int k0 = q * 128;
        float acc = 0.f;
#pragma unroll 8
        for (int k = 0; k < 128; ++k) {
            acc = fmaf(aggr[k0 + k], W1[(size_t)(k0 + k) * HID + j], acc);
        }
        part[q][j] = acc;
    }
    __syncthreads();
    if (t < HID) {
        float acc = part[0][t] + part[1][t] + part[2][t] + part[3][t] + b1[t];
        float v = acc > 0.f ? acc : 1.6732632423543772f * expm1f(acc);  // selu
        hbuf[t] = 1.0507009873554805f * v;
    }
    __syncthreads();
    // --- LayerNorm over HID=50 ---
    if (t < HID) {
        float mu = 0.f;
#pragma unroll
        for (int j2 = 0; j2 < HID; ++j2) mu += hbuf[j2];
        mu *= (1.0f / HID);
        float va = 0.f;
#pragma unroll
        for (int j2 = 0; j2 < HID; ++j2) { float d = hbuf[j2] - mu; va = fmaf(d, d, va); }
        va *= (1.0f / HID);
        hn[t] = (hbuf[t] - mu) * rsqrtf(va + 1e-5f) * lng[t] + lnb[t];
    }
    __syncthreads();
    // --- GEMM2: head = hn(1x50) @ W2(50x201) + b2 ---
    if (t < GDIM_) {
        float acc = b2[t];
#pragma unroll
        for (int j2 = 0; j2 < HID; ++j2) {
            acc = fmaf(hn[j2], W2[(size_t)j2 * GDIM_ + t], acc);
        }
        out[(size_t)g * OUTW + t] = acc;
    }
    // --- tail: u[:, -33:] copy ---
    if (t >= 201 && t < 201 + TAILN) {
        int i2 = t - 201;
        out[(size_t)g * OUTW + GDIM_ + i2] = u[(size_t)g * U_COLS + (U_COLS - TAILN) + i2];
    }
}

extern "C" void kernel_launch(void* const* d_in, const int* in_sizes, int n_in,
                              void* d_out, int out_size, void* d_ws, size_t ws_size,
                              hipStream_t stream) {
    // inputs: x, edge_index, edge_attr, u, batch, W1, b1, ln_g, ln_b, W2, b2
    const float* x     = (const float*)d_in[0];
    const float* u     = (const float*)d_in[3];
    const int*   batch = (const int*)d_in[4];
    const float* W1    = (const float*)d_in[5];
    const float* b1    = (const float*)d_in[6];
    const float* lng   = (const float*)d_in[7];
    const float* lnb   = (const float*)d_in[8];
    const float* W2    = (const float*)d_in[9];
    const float* b2    = (const float*)d_in[10];
    float* out = (float*)d_out;

    pna_main_kernel<<<G_SEG, 256, 0, stream>>>(x, u, batch, W1, b1, lng, lnb, W2, b2, out);
}